// Round 1
// baseline (5862.673 us; speedup 1.0000x reference)
//
#include <hip/hip_runtime.h>
#include <hip/hip_bf16.h>
#include <stdint.h>

#define N_NODES 50000
#define N_EDGES 800000
#define IN_CH 256
#define HID 128
#define OUT_CH 64
#define EDGE_DIM 64

typedef __hip_bfloat16 bf16;

__device__ __forceinline__ void st_out(float* p, float v) { *p = v; }
__device__ __forceinline__ void st_out(bf16* p, float v) { *p = __float2bfloat16(v); }

// Generic persistent row-GEMM: out[r, c] = act( sum_k A[r, koff+k] (+A2) * W[koff+k, c] + b[c] )
// Weights staged fp32 in LDS (<=64KB). 512 threads, SUB rows per block-iteration.
template<int K, int N, int SUB, bool RELU, bool ADD2, bool ACCUM, typename OutT>
__launch_bounds__(512)
__global__ void gemm_rows(const float* __restrict__ A, const float* __restrict__ A2,
                          int lda, int koff,
                          const float* __restrict__ W, const float* __restrict__ b,
                          OutT* __restrict__ out, int M) {
    __shared__ __align__(16) float Ws[K * N];
    __shared__ __align__(16) float As[SUB * K];
    const int tid = threadIdx.x;

    // stage weight block (rows koff..koff+K-1)
    for (int i = tid; i < K * N; i += 512) Ws[i] = W[koff * N + i];
    __syncthreads();

    const int s = tid / N;
    const int c = tid % N;

    for (int base = blockIdx.x * SUB; base < M; base += gridDim.x * SUB) {
        // stage activation rows (optionally summing two inputs)
        for (int i = tid; i < SUB * K; i += 512) {
            int ss = i / K, kk = i % K;
            int r = base + ss;
            float v = 0.f;
            if (r < M) {
                int idx = r * lda + koff + kk;
                v = A[idx];
                if (ADD2) v += A2[idx];
            }
            As[i] = v;
        }
        __syncthreads();

        int r = base + s;
        if (r < M) {
            float acc = ACCUM ? 0.f : b[c];
            const float* as = &As[s * K];
            #pragma unroll
            for (int k = 0; k < K; k += 4) {
                float4 av = *(const float4*)&as[k];
                acc = fmaf(av.x, Ws[(k + 0) * N + c], acc);
                acc = fmaf(av.y, Ws[(k + 1) * N + c], acc);
                acc = fmaf(av.z, Ws[(k + 2) * N + c], acc);
                acc = fmaf(av.w, Ws[(k + 3) * N + c], acc);
            }
            if (RELU) acc = fmaxf(acc, 0.f);
            int o = r * N + c;
            if (ACCUM) {
                ((float*)out)[o] += acc;
            } else {
                st_out(&out[o], acc);
            }
        }
        __syncthreads();  // protect As before next iteration's restage
    }
}

// message + scatter-add: agg[dst] += relu(h[src] + e), 1 thread = (edge, 4 channels)
__launch_bounds__(256)
__global__ void msg_kernel(const int* __restrict__ ei, const float* __restrict__ h,
                           const bf16* __restrict__ e, float* __restrict__ agg) {
    int gid = blockIdx.x * 256 + threadIdx.x;
    int edge = gid >> 5;
    int c4 = (gid & 31) << 2;
    if (edge >= N_EDGES) return;
    int src = ei[edge];
    int dst = ei[N_EDGES + edge];
    float4 hv = *(const float4*)&h[src * HID + c4];
    uint2 ev = *(const uint2*)&e[edge * HID + c4];
    float e0 = __uint_as_float(ev.x << 16);
    float e1 = __uint_as_float(ev.x & 0xffff0000u);
    float e2 = __uint_as_float(ev.y << 16);
    float e3 = __uint_as_float(ev.y & 0xffff0000u);
    float m0 = fmaxf(hv.x + e0, 0.f);
    float m1 = fmaxf(hv.y + e1, 0.f);
    float m2 = fmaxf(hv.z + e2, 0.f);
    float m3 = fmaxf(hv.w + e3, 0.f);
    float* a = &agg[dst * HID + c4];
    atomicAdd(a + 0, m0);
    atomicAdd(a + 1, m1);
    atomicAdd(a + 2, m2);
    atomicAdd(a + 3, m3);
}

extern "C" void kernel_launch(void* const* d_in, const int* in_sizes, int n_in,
                              void* d_out, int out_size, void* d_ws, size_t ws_size,
                              hipStream_t stream) {
    const float* x     = (const float*)d_in[0];
    const int*   ei    = (const int*)d_in[1];
    const float* ea    = (const float*)d_in[2];
    const float* W_in  = (const float*)d_in[3];
    const float* b_in  = (const float*)d_in[4];
    const float* W_e   = (const float*)d_in[5];
    const float* b_e   = (const float*)d_in[6];
    const float* W1    = (const float*)d_in[7];
    const float* b1    = (const float*)d_in[8];
    const float* W2    = (const float*)d_in[9];
    const float* b2    = (const float*)d_in[10];
    const float* W_out = (const float*)d_in[11];
    const float* b_out = (const float*)d_in[12];
    float* out = (float*)d_out;

    char* ws = (char*)d_ws;
    float* h   = (float*)(ws);                                  // 50000*128*4 = 25.6 MB
    float* agg = (float*)(ws + 25600000);                       // 25.6 MB
    bf16*  e   = (bf16*)(ws + 51200000);                        // 800000*128*2 = 204.8 MB

    const int G = 512;       // persistent GEMM grid
    const int B = 512;

    // h = x @ W_in + b_in  (K=256 split into two K=128 passes)
    gemm_rows<128, 128, 4, false, false, false, float>
        <<<G, B, 0, stream>>>(x, nullptr, IN_CH, 0, W_in, b_in, h, N_NODES);
    gemm_rows<128, 128, 4, false, false, true, float>
        <<<G, B, 0, stream>>>(x, nullptr, IN_CH, 128, W_in, nullptr, h, N_NODES);

    // e = edge_attr @ W_e + b_e  (stored bf16)
    gemm_rows<64, 128, 4, false, false, false, bf16>
        <<<G, B, 0, stream>>>(ea, nullptr, EDGE_DIM, 0, W_e, b_e, e, N_EDGES);

    for (int layer = 0; layer < 3; ++layer) {
        hipMemsetAsync(agg, 0, (size_t)N_NODES * HID * sizeof(float), stream);
        msg_kernel<<<(N_EDGES * 32) / 256, 256, 0, stream>>>(ei, h, e, agg);
        // t = relu((h + agg) @ W1 + b1)   (in-place on h: rows staged to LDS first)
        gemm_rows<128, 128, 4, true, true, false, float>
            <<<G, B, 0, stream>>>(h, agg, HID, 0, W1, b1, h, N_NODES);
        // h = relu(t @ W2 + b2)
        gemm_rows<128, 128, 4, true, false, false, float>
            <<<G, B, 0, stream>>>(h, nullptr, HID, 0, W2, b2, h, N_NODES);
    }

    // out = h @ W_out + b_out
    gemm_rows<128, 64, 8, false, false, false, float>
        <<<G, B, 0, stream>>>(h, nullptr, HID, 0, W_out, b_out, out, N_NODES);
}

// Round 2
// 2208.164 us; speedup vs baseline: 2.6550x; 2.6550x over previous
//
#include <hip/hip_runtime.h>
#include <hip/hip_bf16.h>
#include <stdint.h>

#define N_NODES 50000
#define N_EDGES 800000
#define IN_CH 256
#define HID 128
#define OUT_CH 64
#define EDGE_DIM 64

typedef __hip_bfloat16 bf16;

__device__ __forceinline__ void st_out(float* p, float v) { *p = v; }
__device__ __forceinline__ void st_out(bf16* p, float v) { *p = __float2bfloat16(v); }

// Generic persistent row-GEMM: out[orow, c] = act( sum_k A[r, koff+k] * W[koff+k, c] + b[c] )
// orow = PERM ? operm[r] : r. Weights staged fp32 in LDS. 512 threads, SUB rows/iter.
template<int K, int N, int SUB, bool RELU, bool ACCUM, bool PERM, typename OutT>
__launch_bounds__(512)
__global__ void gemm_rows(const float* __restrict__ A, int lda, int koff,
                          const float* __restrict__ W, const float* __restrict__ b,
                          OutT* __restrict__ out, int M, const int* __restrict__ operm) {
    __shared__ __align__(16) float Ws[K * N];
    __shared__ __align__(16) float As[SUB * K];
    const int tid = threadIdx.x;

    for (int i = tid; i < K * N; i += 512) Ws[i] = W[koff * N + i];
    __syncthreads();

    const int s = tid / N;
    const int c = tid % N;

    for (int base = blockIdx.x * SUB; base < M; base += gridDim.x * SUB) {
        for (int i = tid; i < SUB * K; i += 512) {
            int ss = i / K, kk = i % K;
            int r = base + ss;
            As[i] = (r < M) ? A[r * lda + koff + kk] : 0.f;
        }
        __syncthreads();

        int r = base + s;
        if (r < M) {
            float acc = ACCUM ? 0.f : b[c];
            const float* as = &As[s * K];
            #pragma unroll
            for (int k = 0; k < K; k += 4) {
                float4 av = *(const float4*)&as[k];
                acc = fmaf(av.x, Ws[(k + 0) * N + c], acc);
                acc = fmaf(av.y, Ws[(k + 1) * N + c], acc);
                acc = fmaf(av.z, Ws[(k + 2) * N + c], acc);
                acc = fmaf(av.w, Ws[(k + 3) * N + c], acc);
            }
            if (RELU) acc = fmaxf(acc, 0.f);
            int orow = PERM ? operm[r] : r;
            int o = orow * N + c;
            if (ACCUM) {
                ((float*)out)[o] += acc;
            } else {
                st_out(&out[o], acc);
            }
        }
        __syncthreads();
    }
}

// ---- counting sort of edges by dst ----
__launch_bounds__(256)
__global__ void hist_kernel(const int* __restrict__ ei, int* __restrict__ counts) {
    int edge = blockIdx.x * 256 + threadIdx.x;
    if (edge < N_EDGES) atomicAdd(&counts[ei[N_EDGES + edge]], 1);
}

__launch_bounds__(1024)
__global__ void scan_kernel(const int* __restrict__ counts, int* __restrict__ offsets,
                            int* __restrict__ cursor) {
    __shared__ int part[1024];
    const int tid = threadIdx.x;
    const int CH = (N_NODES + 1023) / 1024;  // 49
    int beg = tid * CH, end = min(beg + CH, N_NODES);
    int s = 0;
    for (int i = beg; i < end; i++) s += counts[i];
    part[tid] = s;
    __syncthreads();
    for (int off = 1; off < 1024; off <<= 1) {
        int t = (tid >= off) ? part[tid - off] : 0;
        __syncthreads();
        part[tid] += t;
        __syncthreads();
    }
    int run = (tid == 0) ? 0 : part[tid - 1];
    for (int i = beg; i < end; i++) {
        offsets[i] = run;
        cursor[i] = run;
        run += counts[i];
    }
    if (tid == 1023) offsets[N_NODES] = part[1023];
}

__launch_bounds__(256)
__global__ void scatter_perm(const int* __restrict__ ei, int* __restrict__ cursor,
                             int* __restrict__ pos_of_edge, int* __restrict__ src_sorted) {
    int edge = blockIdx.x * 256 + threadIdx.x;
    if (edge >= N_EDGES) return;
    int dst = ei[N_EDGES + edge];
    int pos = atomicAdd(&cursor[dst], 1);
    pos_of_edge[edge] = pos;
    src_sorted[pos] = ei[edge];
}

// ---- segmented aggregation: z[n] = h[n] + sum_{edges->n} relu(h[src]+e), no atomics ----
// one wave per node; lane owns 2 channels
__launch_bounds__(256)
__global__ void agg_kernel(const int* __restrict__ offsets, const int* __restrict__ src_sorted,
                           const bf16* __restrict__ e, const float* __restrict__ h,
                           float* __restrict__ z) {
    int wid = (blockIdx.x * 256 + threadIdx.x) >> 6;
    int lane = threadIdx.x & 63;
    if (wid >= N_NODES) return;
    int beg = offsets[wid], end = offsets[wid + 1];
    int c = lane * 2;
    float2 acc = {0.f, 0.f};
    int i = beg;
    // 2-edge unroll for 2 outstanding gathers
    for (; i + 1 < end; i += 2) {
        int s0 = src_sorted[i], s1 = src_sorted[i + 1];
        uint32_t ev0 = *(const uint32_t*)&e[i * HID + c];
        uint32_t ev1 = *(const uint32_t*)&e[(i + 1) * HID + c];
        float2 h0 = *(const float2*)&h[s0 * HID + c];
        float2 h1 = *(const float2*)&h[s1 * HID + c];
        acc.x += fmaxf(h0.x + __uint_as_float(ev0 << 16), 0.f);
        acc.y += fmaxf(h0.y + __uint_as_float(ev0 & 0xffff0000u), 0.f);
        acc.x += fmaxf(h1.x + __uint_as_float(ev1 << 16), 0.f);
        acc.y += fmaxf(h1.y + __uint_as_float(ev1 & 0xffff0000u), 0.f);
    }
    if (i < end) {
        int s0 = src_sorted[i];
        uint32_t ev0 = *(const uint32_t*)&e[i * HID + c];
        float2 h0 = *(const float2*)&h[s0 * HID + c];
        acc.x += fmaxf(h0.x + __uint_as_float(ev0 << 16), 0.f);
        acc.y += fmaxf(h0.y + __uint_as_float(ev0 & 0xffff0000u), 0.f);
    }
    float2 hv = *(const float2*)&h[wid * HID + c];
    acc.x += hv.x;
    acc.y += hv.y;
    *(float2*)&z[wid * HID + c] = acc;
}

extern "C" void kernel_launch(void* const* d_in, const int* in_sizes, int n_in,
                              void* d_out, int out_size, void* d_ws, size_t ws_size,
                              hipStream_t stream) {
    const float* x     = (const float*)d_in[0];
    const int*   ei    = (const int*)d_in[1];
    const float* ea    = (const float*)d_in[2];
    const float* W_in  = (const float*)d_in[3];
    const float* b_in  = (const float*)d_in[4];
    const float* W_e   = (const float*)d_in[5];
    const float* b_e   = (const float*)d_in[6];
    const float* W1    = (const float*)d_in[7];
    const float* b1    = (const float*)d_in[8];
    const float* W2    = (const float*)d_in[9];
    const float* b2    = (const float*)d_in[10];
    const float* W_out = (const float*)d_in[11];
    const float* b_out = (const float*)d_in[12];
    float* out = (float*)d_out;

    char* ws = (char*)d_ws;
    size_t off = 0;
    float* h       = (float*)(ws + off); off += (size_t)N_NODES * HID * 4;     // 25.6 MB
    float* z       = (float*)(ws + off); off += (size_t)N_NODES * HID * 4;     // 25.6 MB
    bf16*  e       = (bf16*) (ws + off); off += (size_t)N_EDGES * HID * 2;     // 204.8 MB
    int*   counts  = (int*)  (ws + off); off += (size_t)N_NODES * 4;
    int*   offsets = (int*)  (ws + off); off += (size_t)(N_NODES + 1) * 4;
    int*   cursor  = (int*)  (ws + off); off += (size_t)N_NODES * 4;
    int*   poe     = (int*)  (ws + off); off += (size_t)N_EDGES * 4;           // pos_of_edge
    int*   srcs    = (int*)  (ws + off); off += (size_t)N_EDGES * 4;           // src_sorted

    const int G = 512;
    const int B = 512;

    // ---- counting sort by dst ----
    hipMemsetAsync(counts, 0, (size_t)N_NODES * 4, stream);
    hist_kernel<<<(N_EDGES + 255) / 256, 256, 0, stream>>>(ei, counts);
    scan_kernel<<<1, 1024, 0, stream>>>(counts, offsets, cursor);
    scatter_perm<<<(N_EDGES + 255) / 256, 256, 0, stream>>>(ei, cursor, poe, srcs);

    // h = x @ W_in + b_in  (K=256 split into two K=128 passes)
    gemm_rows<128, 128, 4, false, false, false, float>
        <<<G, B, 0, stream>>>(x, IN_CH, 0, W_in, b_in, h, N_NODES, nullptr);
    gemm_rows<128, 128, 4, false, true, false, float>
        <<<G, B, 0, stream>>>(x, IN_CH, 128, W_in, nullptr, h, N_NODES, nullptr);

    // e_sorted[poe[r]] = edge_attr[r] @ W_e + b_e  (bf16, scatter-write into dst-sorted order)
    gemm_rows<64, 128, 4, false, false, true, bf16>
        <<<G, B, 0, stream>>>(ea, EDGE_DIM, 0, W_e, b_e, e, N_EDGES, poe);

    for (int layer = 0; layer < 3; ++layer) {
        // z = h + segment_sum(relu(h[src]+e))  — no atomics
        agg_kernel<<<(N_NODES * 64 + 255) / 256, 256, 0, stream>>>(offsets, srcs, e, h, z);
        // h = relu(z @ W1 + b1)
        gemm_rows<128, 128, 4, true, false, false, float>
            <<<G, B, 0, stream>>>(z, HID, 0, W1, b1, h, N_NODES, nullptr);
        // h = relu(h @ W2 + b2)   (in-place safe: rows staged to LDS first)
        gemm_rows<128, 128, 4, true, false, false, float>
            <<<G, B, 0, stream>>>(h, HID, 0, W2, b2, h, N_NODES, nullptr);
    }

    // out = h @ W_out + b_out
    gemm_rows<128, 64, 8, false, false, false, float>
        <<<G, B, 0, stream>>>(h, HID, 0, W_out, b_out, out, N_NODES, nullptr);
}

// Round 3
// 1047.356 us; speedup vs baseline: 5.5976x; 2.1083x over previous
//
#include <hip/hip_runtime.h>
#include <hip/hip_bf16.h>
#include <stdint.h>

#define N_NODES 50000
#define N_EDGES 800000
#define IN_CH 256
#define HID 128
#define OUT_CH 64
#define EDGE_DIM 64

typedef __hip_bfloat16 bf16;
typedef __attribute__((ext_vector_type(8))) short short8;
typedef __attribute__((ext_vector_type(4))) float f32x4;

__device__ __forceinline__ void st_out(float* p, float v) { *p = v; }
__device__ __forceinline__ void st_out(bf16* p, float v) { *p = __float2bfloat16(v); }

// transpose-convert weights: Wt[n*K + k] = bf16(W[k*N + n])
__launch_bounds__(256)
__global__ void wt_prep(const float* __restrict__ W, bf16* __restrict__ Wt, int K, int N) {
    int i = blockIdx.x * 256 + threadIdx.x;
    if (i >= K * N) return;
    int n = i % N, k = i / N;
    Wt[n * K + k] = __float2bfloat16(W[i]);
}

// MFMA GEMM: out[orow, c] = act( A[r,:] @ W[:,c] + b[c] ), A fp32 [M x KTOT] row-major,
// Wt bf16 [N x KTOT] (pre-transposed). Block = 256 thr = 4 waves, 64-row tile.
template<int KTOT, int N, bool RELU, bool PERM, typename OutT>
__launch_bounds__(256)
__global__ void gemm_mfma(const float* __restrict__ A, const bf16* __restrict__ Wt,
                          const float* __restrict__ b, OutT* __restrict__ out,
                          int M, const int* __restrict__ operm) {
    constexpr int KC  = (KTOT >= 128) ? 128 : KTOT;   // K-chunk staged per pass
    constexpr int NCH = KTOT / KC;
    constexpr int KCP = KC + 8;                        // +16B pad: 2-way bank alias (free)
    constexpr int NT  = N / 16;
    __shared__ __align__(16) bf16 Ws[N * KCP];
    __shared__ __align__(16) bf16 As[64 * KCP];

    const int tid  = threadIdx.x;
    const int wave = tid >> 6;
    const int lane = tid & 63;
    const int quad = lane >> 4;
    const int l16  = lane & 15;
    const int base = blockIdx.x * 64;

    f32x4 acc[NT];
    #pragma unroll
    for (int i = 0; i < NT; i++) acc[i] = (f32x4){0.f, 0.f, 0.f, 0.f};

    for (int ch = 0; ch < NCH; ch++) {
        const int kc = ch * KC;
        // stage weight chunk (bf16, already transposed): 4 elems/thread/iter
        for (int t = tid * 4; t < N * KC; t += 256 * 4) {
            int n = t / KC, k = t % KC;
            *(uint2*)&Ws[n * KCP + k] = *(const uint2*)&Wt[n * KTOT + kc + k];
        }
        // stage A chunk, fp32 -> bf16
        for (int t = tid * 4; t < 64 * KC; t += 256 * 4) {
            int r = t / KC, k = t % KC;
            int gr = base + r;
            float4 v = (gr < M) ? *(const float4*)&A[(size_t)gr * KTOT + kc + k]
                                : make_float4(0.f, 0.f, 0.f, 0.f);
            __hip_bfloat162 p0 = __float22bfloat162_rn(make_float2(v.x, v.y));
            __hip_bfloat162 p1 = __float22bfloat162_rn(make_float2(v.z, v.w));
            *(__hip_bfloat162*)&As[r * KCP + k]     = p0;
            *(__hip_bfloat162*)&As[r * KCP + k + 2] = p1;
        }
        __syncthreads();

        const bf16* arow = &As[(wave * 16 + l16) * KCP];
        #pragma unroll
        for (int ks = 0; ks < KC / 32; ks++) {
            short8 af = *(const short8*)&arow[ks * 32 + quad * 8];
            #pragma unroll
            for (int nt = 0; nt < NT; nt++) {
                short8 bfr = *(const short8*)&Ws[(nt * 16 + l16) * KCP + ks * 32 + quad * 8];
                acc[nt] = __builtin_amdgcn_mfma_f32_16x16x32_bf16(af, bfr, acc[nt], 0, 0, 0);
            }
        }
        __syncthreads();  // protect LDS before next chunk restage
    }

    // epilogue: C/D layout col=lane&15, row=quad*4+reg
    const int r0 = base + wave * 16 + quad * 4;
    #pragma unroll
    for (int reg = 0; reg < 4; reg++) {
        int gr = r0 + reg;
        if (gr < M) {
            int orow = PERM ? operm[gr] : gr;
            #pragma unroll
            for (int nt = 0; nt < NT; nt++) {
                int col = nt * 16 + l16;
                float v = acc[nt][reg] + b[col];
                if (RELU) v = fmaxf(v, 0.f);
                st_out(&out[(size_t)orow * N + col], v);
            }
        }
    }
}

// ---- counting sort of edges by dst ----
__launch_bounds__(256)
__global__ void hist_kernel(const int* __restrict__ ei, int* __restrict__ counts) {
    int edge = blockIdx.x * 256 + threadIdx.x;
    if (edge < N_EDGES) atomicAdd(&counts[ei[N_EDGES + edge]], 1);
}

__launch_bounds__(1024)
__global__ void scan_kernel(const int* __restrict__ counts, int* __restrict__ offsets,
                            int* __restrict__ cursor) {
    __shared__ int part[1024];
    const int tid = threadIdx.x;
    const int CH = (N_NODES + 1023) / 1024;  // 49
    int beg = tid * CH, end = min(beg + CH, N_NODES);
    int s = 0;
    for (int i = beg; i < end; i++) s += counts[i];
    part[tid] = s;
    __syncthreads();
    for (int off = 1; off < 1024; off <<= 1) {
        int t = (tid >= off) ? part[tid - off] : 0;
        __syncthreads();
        part[tid] += t;
        __syncthreads();
    }
    int run = (tid == 0) ? 0 : part[tid - 1];
    for (int i = beg; i < end; i++) {
        offsets[i] = run;
        cursor[i] = run;
        run += counts[i];
    }
    if (tid == 1023) offsets[N_NODES] = part[1023];
}

__launch_bounds__(256)
__global__ void scatter_perm(const int* __restrict__ ei, int* __restrict__ cursor,
                             int* __restrict__ pos_of_edge, int* __restrict__ src_sorted) {
    int edge = blockIdx.x * 256 + threadIdx.x;
    if (edge >= N_EDGES) return;
    int dst = ei[N_EDGES + edge];
    int pos = atomicAdd(&cursor[dst], 1);
    pos_of_edge[edge] = pos;
    src_sorted[pos] = ei[edge];
}

// ---- segmented aggregation: z[n] = h[n] + sum_{edges->n} relu(h[src]+e), no atomics ----
__launch_bounds__(256)
__global__ void agg_kernel(const int* __restrict__ offsets, const int* __restrict__ src_sorted,
                           const bf16* __restrict__ e, const float* __restrict__ h,
                           float* __restrict__ z) {
    int wid = (blockIdx.x * 256 + threadIdx.x) >> 6;
    int lane = threadIdx.x & 63;
    if (wid >= N_NODES) return;
    int beg = offsets[wid], end = offsets[wid + 1];
    int c = lane * 2;
    float2 acc = {0.f, 0.f};
    int i = beg;
    for (; i + 1 < end; i += 2) {
        int s0 = src_sorted[i], s1 = src_sorted[i + 1];
        uint32_t ev0 = *(const uint32_t*)&e[i * HID + c];
        uint32_t ev1 = *(const uint32_t*)&e[(i + 1) * HID + c];
        float2 h0 = *(const float2*)&h[s0 * HID + c];
        float2 h1 = *(const float2*)&h[s1 * HID + c];
        acc.x += fmaxf(h0.x + __uint_as_float(ev0 << 16), 0.f);
        acc.y += fmaxf(h0.y + __uint_as_float(ev0 & 0xffff0000u), 0.f);
        acc.x += fmaxf(h1.x + __uint_as_float(ev1 << 16), 0.f);
        acc.y += fmaxf(h1.y + __uint_as_float(ev1 & 0xffff0000u), 0.f);
    }
    if (i < end) {
        int s0 = src_sorted[i];
        uint32_t ev0 = *(const uint32_t*)&e[i * HID + c];
        float2 h0 = *(const float2*)&h[s0 * HID + c];
        acc.x += fmaxf(h0.x + __uint_as_float(ev0 << 16), 0.f);
        acc.y += fmaxf(h0.y + __uint_as_float(ev0 & 0xffff0000u), 0.f);
    }
    float2 hv = *(const float2*)&h[wid * HID + c];
    acc.x += hv.x;
    acc.y += hv.y;
    *(float2*)&z[wid * HID + c] = acc;
}

extern "C" void kernel_launch(void* const* d_in, const int* in_sizes, int n_in,
                              void* d_out, int out_size, void* d_ws, size_t ws_size,
                              hipStream_t stream) {
    const float* x     = (const float*)d_in[0];
    const int*   ei    = (const int*)d_in[1];
    const float* ea    = (const float*)d_in[2];
    const float* W_in  = (const float*)d_in[3];
    const float* b_in  = (const float*)d_in[4];
    const float* W_e   = (const float*)d_in[5];
    const float* b_e   = (const float*)d_in[6];
    const float* W1    = (const float*)d_in[7];
    const float* b1    = (const float*)d_in[8];
    const float* W2    = (const float*)d_in[9];
    const float* b2    = (const float*)d_in[10];
    const float* W_out = (const float*)d_in[11];
    const float* b_out = (const float*)d_in[12];
    float* out = (float*)d_out;

    char* ws = (char*)d_ws;
    size_t off = 0;
    float* h       = (float*)(ws + off); off += (size_t)N_NODES * HID * 4;
    float* z       = (float*)(ws + off); off += (size_t)N_NODES * HID * 4;
    bf16*  e       = (bf16*) (ws + off); off += (size_t)N_EDGES * HID * 2;
    int*   counts  = (int*)  (ws + off); off += (size_t)N_NODES * 4;
    int*   offsets = (int*)  (ws + off); off += (size_t)(N_NODES + 1) * 4;
    int*   cursor  = (int*)  (ws + off); off += (size_t)N_NODES * 4;
    int*   poe     = (int*)  (ws + off); off += (size_t)N_EDGES * 4;
    int*   srcs    = (int*)  (ws + off); off += (size_t)N_EDGES * 4;
    bf16*  Wt_in   = (bf16*) (ws + off); off += (size_t)HID * IN_CH * 2;
    bf16*  Wt_e    = (bf16*) (ws + off); off += (size_t)HID * EDGE_DIM * 2;
    bf16*  Wt_1    = (bf16*) (ws + off); off += (size_t)HID * HID * 2;
    bf16*  Wt_2    = (bf16*) (ws + off); off += (size_t)HID * HID * 2;
    bf16*  Wt_out  = (bf16*) (ws + off); off += (size_t)OUT_CH * HID * 2;

    // ---- weight prep (transpose + bf16) ----
    wt_prep<<<(IN_CH * HID + 255) / 256, 256, 0, stream>>>(W_in, Wt_in, IN_CH, HID);
    wt_prep<<<(EDGE_DIM * HID + 255) / 256, 256, 0, stream>>>(W_e, Wt_e, EDGE_DIM, HID);
    wt_prep<<<(HID * HID + 255) / 256, 256, 0, stream>>>(W1, Wt_1, HID, HID);
    wt_prep<<<(HID * HID + 255) / 256, 256, 0, stream>>>(W2, Wt_2, HID, HID);
    wt_prep<<<(HID * OUT_CH + 255) / 256, 256, 0, stream>>>(W_out, Wt_out, HID, OUT_CH);

    // ---- counting sort by dst ----
    hipMemsetAsync(counts, 0, (size_t)N_NODES * 4, stream);
    hist_kernel<<<(N_EDGES + 255) / 256, 256, 0, stream>>>(ei, counts);
    scan_kernel<<<1, 1024, 0, stream>>>(counts, offsets, cursor);
    scatter_perm<<<(N_EDGES + 255) / 256, 256, 0, stream>>>(ei, cursor, poe, srcs);

    const int GN = (N_NODES + 63) / 64;   // 782
    const int GE = (N_EDGES + 63) / 64;   // 12500

    // h = x @ W_in + b_in  (K=256, 2 chunks in-kernel)
    gemm_mfma<IN_CH, HID, false, false, float>
        <<<GN, 256, 0, stream>>>(x, Wt_in, b_in, h, N_NODES, nullptr);

    // e_sorted[poe[r]] = edge_attr @ W_e + b_e (bf16, scatter into dst-sorted order)
    gemm_mfma<EDGE_DIM, HID, false, true, bf16>
        <<<GE, 256, 0, stream>>>(ea, Wt_e, b_e, e, N_EDGES, poe);

    for (int layer = 0; layer < 3; ++layer) {
        agg_kernel<<<(N_NODES * 64 + 255) / 256, 256, 0, stream>>>(offsets, srcs, e, h, z);
        gemm_mfma<HID, HID, true, false, float>
            <<<GN, 256, 0, stream>>>(z, Wt_1, b1, h, N_NODES, nullptr);   // h = relu(z@W1+b1)
        gemm_mfma<HID, HID, true, false, float>
            <<<GN, 256, 0, stream>>>(h, Wt_2, b2, z, N_NODES, nullptr);   // z = relu(h@W2+b2)
        // swap roles: next layer's h is z
        float* t = h; h = z; z = t;
    }

    // out = h @ W_out + b_out
    gemm_mfma<HID, OUT_CH, false, false, float>
        <<<GN, 256, 0, stream>>>(h, Wt_out, b_out, out, N_NODES, nullptr);
}

// Round 4
// 886.841 us; speedup vs baseline: 6.6107x; 1.1810x over previous
//
#include <hip/hip_runtime.h>
#include <hip/hip_bf16.h>
#include <stdint.h>

#define N_NODES 50000
#define N_EDGES 800000
#define IN_CH 256
#define HID 128
#define OUT_CH 64
#define EDGE_DIM 64

typedef __hip_bfloat16 bf16;
typedef __attribute__((ext_vector_type(8))) short short8;
typedef __attribute__((ext_vector_type(4))) float f32x4;

__device__ __forceinline__ void st_out(float* p, float v) { *p = v; }
__device__ __forceinline__ void st_out(bf16* p, float v) { *p = __float2bfloat16(v); }

// ---- one-shot weight prep: transpose + bf16 for all 5 weight matrices ----
// Wt[n*K + k] = bf16(W[k*N + n])
__device__ __forceinline__ void wt_one(const float* W, bf16* Wt, int K, int N, int i) {
    int n = i % N, k = i / N;
    Wt[n * K + k] = __float2bfloat16(W[i]);
}
__launch_bounds__(256)
__global__ void wt_prep_all(const float* W_in, const float* W_e, const float* W1,
                            const float* W2, const float* W_out,
                            bf16* Wt_in, bf16* Wt_e, bf16* Wt_1, bf16* Wt_2, bf16* Wt_out) {
    int i = blockIdx.x * 256 + threadIdx.x;
    if (i < 32768)       wt_one(W_in,  Wt_in,  256, 128, i);
    else if (i < 40960)  wt_one(W_e,   Wt_e,    64, 128, i - 32768);
    else if (i < 57344)  wt_one(W1,    Wt_1,   128, 128, i - 40960);
    else if (i < 73728)  wt_one(W2,    Wt_2,   128, 128, i - 57344);
    else if (i < 81920)  wt_one(W_out, Wt_out, 128,  64, i - 73728);
}

// MFMA GEMM: out[orow, c] = act( A[r,:] @ W[:,c] + b[c] )
// A: InT [M x KTOT] row-major (fp32 converted at staging, bf16 copied).
// Wt: bf16 [N x KTOT] pre-transposed. 256 thr = 4 waves; MROWS-row block tile.
template<int KTOT, int N, int MROWS, bool RELU, bool PERM, typename InT, typename OutT>
__launch_bounds__(256)
__global__ void gemm_mfma(const InT* __restrict__ A, const bf16* __restrict__ Wt,
                          const float* __restrict__ b, OutT* __restrict__ out,
                          int M, const int* __restrict__ operm) {
    static_assert(KTOT % 64 == 0, "");
    constexpr int KC  = 64;
    constexpr int NCH = KTOT / KC;
    constexpr int KCP = KC + 8;            // 72: row = 144 B (16B-aligned, 2-way bank alias = free)
    constexpr int NT  = N / 16;
    constexpr int MT  = MROWS / 64;        // m-tiles per wave
    __shared__ __align__(16) bf16 Ws[N * KCP];
    __shared__ __align__(16) bf16 As[MROWS * KCP];

    const int tid  = threadIdx.x;
    const int wave = tid >> 6;
    const int lane = tid & 63;
    const int quad = lane >> 4;
    const int l16  = lane & 15;
    const int base = blockIdx.x * MROWS;

    f32x4 acc[MT][NT];
    #pragma unroll
    for (int m = 0; m < MT; m++)
        #pragma unroll
        for (int i = 0; i < NT; i++) acc[m][i] = (f32x4){0.f, 0.f, 0.f, 0.f};

    for (int ch = 0; ch < NCH; ch++) {
        const int kc = ch * KC;
        // stage weight chunk (bf16 16B copies)
        constexpr int WIT = N * KC / (256 * 8);
        #pragma unroll
        for (int it = 0; it < WIT; it++) {
            int t8 = (it * 256 + tid) * 8;
            int n = t8 / KC, k = t8 % KC;
            *(uint4*)&Ws[n * KCP + k] = *(const uint4*)&Wt[n * KTOT + kc + k];
        }
        // stage A chunk
        if constexpr (sizeof(InT) == 4) {
            constexpr int AIT = MROWS * KC / (256 * 4);
            #pragma unroll
            for (int it = 0; it < AIT; it++) {
                int t4 = (it * 256 + tid) * 4;
                int r = t4 / KC, k = t4 % KC;
                int gr = base + r;
                float4 v = (gr < M) ? *(const float4*)&A[(size_t)gr * KTOT + kc + k]
                                    : make_float4(0.f, 0.f, 0.f, 0.f);
                *(__hip_bfloat162*)&As[r * KCP + k]     = __float22bfloat162_rn(make_float2(v.x, v.y));
                *(__hip_bfloat162*)&As[r * KCP + k + 2] = __float22bfloat162_rn(make_float2(v.z, v.w));
            }
        } else {
            constexpr int AIT = MROWS * KC / (256 * 8);
            #pragma unroll
            for (int it = 0; it < AIT; it++) {
                int t8 = (it * 256 + tid) * 8;
                int r = t8 / KC, k = t8 % KC;
                int gr = base + r;
                uint4 v = (gr < M) ? *(const uint4*)&A[(size_t)gr * KTOT + kc + k]
                                   : make_uint4(0u, 0u, 0u, 0u);
                *(uint4*)&As[r * KCP + k] = v;
            }
        }
        __syncthreads();

        #pragma unroll
        for (int ks = 0; ks < KC / 32; ks++) {
            short8 af[MT];
            #pragma unroll
            for (int m = 0; m < MT; m++)
                af[m] = *(const short8*)&As[(wave * MT * 16 + m * 16 + l16) * KCP + ks * 32 + quad * 8];
            #pragma unroll
            for (int nt = 0; nt < NT; nt++) {
                short8 bfr = *(const short8*)&Ws[(nt * 16 + l16) * KCP + ks * 32 + quad * 8];
                #pragma unroll
                for (int m = 0; m < MT; m++)
                    acc[m][nt] = __builtin_amdgcn_mfma_f32_16x16x32_bf16(af[m], bfr, acc[m][nt], 0, 0, 0);
            }
        }
        __syncthreads();
    }

    // epilogue: C/D layout col=lane&15, row=quad*4+reg
    #pragma unroll
    for (int m = 0; m < MT; m++) {
        const int r0 = base + wave * MT * 16 + m * 16 + quad * 4;
        #pragma unroll
        for (int reg = 0; reg < 4; reg++) {
            int gr = r0 + reg;
            if (gr < M) {
                int orow = PERM ? operm[gr] : gr;
                #pragma unroll
                for (int nt = 0; nt < NT; nt++) {
                    int col = nt * 16 + l16;
                    float v = acc[m][nt][reg] + b[col];
                    if (RELU) v = fmaxf(v, 0.f);
                    st_out(&out[(size_t)orow * N + col], v);
                }
            }
        }
    }
}

// ---- counting sort of edges by dst ----
__launch_bounds__(256)
__global__ void hist_kernel(const int* __restrict__ ei, int* __restrict__ counts) {
    int edge = blockIdx.x * 256 + threadIdx.x;
    if (edge < N_EDGES) atomicAdd(&counts[ei[N_EDGES + edge]], 1);
}

__launch_bounds__(1024)
__global__ void scan_kernel(const int* __restrict__ counts, int* __restrict__ offsets,
                            int* __restrict__ cursor) {
    __shared__ int part[1024];
    const int tid = threadIdx.x;
    const int CH = (N_NODES + 1023) / 1024;
    int beg = tid * CH, end = min(beg + CH, N_NODES);
    int s = 0;
    for (int i = beg; i < end; i++) s += counts[i];
    part[tid] = s;
    __syncthreads();
    for (int off = 1; off < 1024; off <<= 1) {
        int t = (tid >= off) ? part[tid - off] : 0;
        __syncthreads();
        part[tid] += t;
        __syncthreads();
    }
    int run = (tid == 0) ? 0 : part[tid - 1];
    for (int i = beg; i < end; i++) {
        offsets[i] = run;
        cursor[i] = run;
        run += counts[i];
    }
    if (tid == 1023) offsets[N_NODES] = part[1023];
}

__launch_bounds__(256)
__global__ void scatter_perm(const int* __restrict__ ei, int* __restrict__ cursor,
                             int* __restrict__ pos_of_edge, int* __restrict__ src_sorted) {
    int edge = blockIdx.x * 256 + threadIdx.x;
    if (edge >= N_EDGES) return;
    int dst = ei[N_EDGES + edge];
    int pos = atomicAdd(&cursor[dst], 1);
    pos_of_edge[edge] = pos;
    src_sorted[pos] = ei[edge];
}

// ---- segmented aggregation (all bf16): z[n] = h[n] + sum_{e->n} relu(h[src]+e) ----
__device__ __forceinline__ float blo(uint32_t u) { return __uint_as_float(u << 16); }
__device__ __forceinline__ float bhi(uint32_t u) { return __uint_as_float(u & 0xffff0000u); }

__launch_bounds__(256)
__global__ void agg_kernel(const int* __restrict__ offsets, const int* __restrict__ src_sorted,
                           const bf16* __restrict__ e, const bf16* __restrict__ h,
                           bf16* __restrict__ z) {
    int wid = (blockIdx.x * 256 + threadIdx.x) >> 6;
    int lane = threadIdx.x & 63;
    if (wid >= N_NODES) return;
    int beg = offsets[wid], end = offsets[wid + 1];
    int c = lane * 2;
    float2 acc = {0.f, 0.f};
    int i = beg;
    for (; i + 1 < end; i += 2) {
        int s0 = src_sorted[i], s1 = src_sorted[i + 1];
        uint32_t ev0 = *(const uint32_t*)&e[i * HID + c];
        uint32_t ev1 = *(const uint32_t*)&e[(i + 1) * HID + c];
        uint32_t h0 = *(const uint32_t*)&h[s0 * HID + c];
        uint32_t h1 = *(const uint32_t*)&h[s1 * HID + c];
        acc.x += fmaxf(blo(h0) + blo(ev0), 0.f);
        acc.y += fmaxf(bhi(h0) + bhi(ev0), 0.f);
        acc.x += fmaxf(blo(h1) + blo(ev1), 0.f);
        acc.y += fmaxf(bhi(h1) + bhi(ev1), 0.f);
    }
    if (i < end) {
        int s0 = src_sorted[i];
        uint32_t ev0 = *(const uint32_t*)&e[i * HID + c];
        uint32_t h0 = *(const uint32_t*)&h[s0 * HID + c];
        acc.x += fmaxf(blo(h0) + blo(ev0), 0.f);
        acc.y += fmaxf(bhi(h0) + bhi(ev0), 0.f);
    }
    uint32_t hs = *(const uint32_t*)&h[wid * HID + c];
    acc.x += blo(hs);
    acc.y += bhi(hs);
    __hip_bfloat162 p = __float22bfloat162_rn(make_float2(acc.x, acc.y));
    *(__hip_bfloat162*)&z[wid * HID + c] = p;
}

extern "C" void kernel_launch(void* const* d_in, const int* in_sizes, int n_in,
                              void* d_out, int out_size, void* d_ws, size_t ws_size,
                              hipStream_t stream) {
    const float* x     = (const float*)d_in[0];
    const int*   ei    = (const int*)d_in[1];
    const float* ea    = (const float*)d_in[2];
    const float* W_in  = (const float*)d_in[3];
    const float* b_in  = (const float*)d_in[4];
    const float* W_e   = (const float*)d_in[5];
    const float* b_e   = (const float*)d_in[6];
    const float* W1    = (const float*)d_in[7];
    const float* b1    = (const float*)d_in[8];
    const float* W2    = (const float*)d_in[9];
    const float* b2    = (const float*)d_in[10];
    const float* W_out = (const float*)d_in[11];
    const float* b_out = (const float*)d_in[12];
    float* out = (float*)d_out;

    char* ws = (char*)d_ws;
    size_t off = 0;
    bf16*  h       = (bf16*) (ws + off); off += (size_t)N_NODES * HID * 2;     // 12.8 MB
    bf16*  z       = (bf16*) (ws + off); off += (size_t)N_NODES * HID * 2;     // 12.8 MB
    bf16*  e       = (bf16*) (ws + off); off += (size_t)N_EDGES * HID * 2;     // 204.8 MB
    int*   counts  = (int*)  (ws + off); off += (size_t)N_NODES * 4;
    int*   offsets = (int*)  (ws + off); off += (size_t)(N_NODES + 1) * 4;
    int*   cursor  = (int*)  (ws + off); off += (size_t)N_NODES * 4;
    int*   poe     = (int*)  (ws + off); off += (size_t)N_EDGES * 4;
    int*   srcs    = (int*)  (ws + off); off += (size_t)N_EDGES * 4;
    bf16*  Wt_in   = (bf16*) (ws + off); off += (size_t)HID * IN_CH * 2;
    bf16*  Wt_e    = (bf16*) (ws + off); off += (size_t)HID * EDGE_DIM * 2;
    bf16*  Wt_1    = (bf16*) (ws + off); off += (size_t)HID * HID * 2;
    bf16*  Wt_2    = (bf16*) (ws + off); off += (size_t)HID * HID * 2;
    bf16*  Wt_out  = (bf16*) (ws + off); off += (size_t)OUT_CH * HID * 2;

    // ---- weight prep (one kernel) ----
    wt_prep_all<<<(81920 + 255) / 256, 256, 0, stream>>>(
        W_in, W_e, W1, W2, W_out, Wt_in, Wt_e, Wt_1, Wt_2, Wt_out);

    // ---- counting sort by dst ----
    hipMemsetAsync(counts, 0, (size_t)N_NODES * 4, stream);
    hist_kernel<<<(N_EDGES + 255) / 256, 256, 0, stream>>>(ei, counts);
    scan_kernel<<<1, 1024, 0, stream>>>(counts, offsets, cursor);
    scatter_perm<<<(N_EDGES + 255) / 256, 256, 0, stream>>>(ei, cursor, poe, srcs);

    // h = x @ W_in + b_in   (fp32 in, bf16 out)
    gemm_mfma<IN_CH, HID, 64, false, false, float, bf16>
        <<<(N_NODES + 63) / 64, 256, 0, stream>>>(x, Wt_in, b_in, h, N_NODES, nullptr);

    // e_sorted[poe[r]] = edge_attr @ W_e + b_e (128-row tile, scatter into sorted order)
    gemm_mfma<EDGE_DIM, HID, 128, false, true, float, bf16>
        <<<(N_EDGES + 127) / 128, 256, 0, stream>>>(ea, Wt_e, b_e, e, N_EDGES, poe);

    for (int layer = 0; layer < 3; ++layer) {
        agg_kernel<<<(N_NODES * 64 + 255) / 256, 256, 0, stream>>>(offsets, srcs, e, h, z);
        gemm_mfma<HID, HID, 64, true, false, bf16, bf16>
            <<<(N_NODES + 63) / 64, 256, 0, stream>>>(z, Wt_1, b1, h, N_NODES, nullptr);
        gemm_mfma<HID, HID, 64, true, false, bf16, bf16>
            <<<(N_NODES + 63) / 64, 256, 0, stream>>>(h, Wt_2, b2, z, N_NODES, nullptr);
        bf16* t = h; h = z; z = t;   // next layer's h is g2's output
    }

    // out = h @ W_out + b_out (fp32 out)
    gemm_mfma<HID, OUT_CH, 64, false, false, bf16, float>
        <<<(N_NODES + 63) / 64, 256, 0, stream>>>(h, Wt_out, b_out, out, N_NODES, nullptr);
}